// Round 11
// baseline (675.687 us; speedup 1.0000x reference)
//
#include <hip/hip_runtime.h>
#include <hip/hip_bf16.h>

#define N_DEST 8192
#define N_SRC  8192
#define FEATD  1024
#define TFDIM  256
#define EMBD   64
#define HIDD   128
#define LDO    1024   // out1 row stride (f32). ws path uses only [512,768)
                      // (g_dst f32); fallback path uses [0,768).
#define SCAP 240      // fast-path capacity (count>SCAP -> dense path)

typedef float  f32x4  __attribute__((ext_vector_type(4)));
typedef __bf16 bf16x8 __attribute__((ext_vector_type(8)));
typedef unsigned short u16x4 __attribute__((ext_vector_type(4)));

__device__ inline bf16x8 load8cvt(const float* p) {
  const f32x4 u = *(const f32x4*)p;
  const f32x4 v = *(const f32x4*)(p + 4);
  bf16x8 r;
  #pragma unroll
  for (int i = 0; i < 4; ++i) { r[i] = (__bf16)u[i]; r[i + 4] = (__bf16)v[i]; }
  return r;
}
__device__ inline unsigned short bfbits(float f) {
  __bf16 b = (__bf16)f;
  return *(unsigned short*)&b;
}
__device__ inline float bf2f(unsigned short u) {
  union { unsigned int i; float f; } x;
  x.i = (unsigned int)u << 16;
  return x.f;
}

// ---------------------------------------------------------------------------
// K0 — one-shot weight conversion: fc_W and dec_W f32 -> bf16 bits in ws.
// ---------------------------------------------------------------------------
__global__ __launch_bounds__(256) void cvt_weights(
    const float* __restrict__ fc_W, const float* __restrict__ dec_W,
    unsigned short* __restrict__ wpack, unsigned short* __restrict__ dpack)
{
  const int which = blockIdx.x >> 8;  // 0: fc_W, 1: dec_W (both 262144 elems)
  const int i = ((blockIdx.x & 255) * 256 + threadIdx.x) * 4;
  const float* src = which ? dec_W : fc_W;
  unsigned short* dst = which ? dpack : wpack;
  const f32x4 v = *(const f32x4*)(src + i);
  u16x4 o;
  #pragma unroll
  for (int e = 0; e < 4; ++e) o[e] = bfbits(v[e]);
  *(u16x4*)(dst + i) = o;
}

// ---------------------------------------------------------------------------
// K1 — MFMA GEMM: transformed = feature_src @ fc_W^T + fc_b.
// 64x64 tile, 4 waves. ws path: writes ONLY dense apack (stage f32 for
// transformed is dead — attn dense path reads apack now). Fallback: f32.
// ---------------------------------------------------------------------------
__global__ __launch_bounds__(256) void gemm_mfma_k1(
    const float* __restrict__ A, const float* __restrict__ B,
    const float* __restrict__ bias, float* __restrict__ stage,
    unsigned short* __restrict__ apack,
    const unsigned short* __restrict__ wpack)
{
  const int wave = threadIdx.x >> 6, lane = threadIdx.x & 63;
  const int l15 = lane & 15, quad = lane >> 4;
  const int row0 = blockIdx.x * 64 + wave * 16;
  const int col0 = blockIdx.y * 64;

  const float* Ap = A + (size_t)(row0 + l15) * FEATD + quad * 8;

  f32x4 acc[4];
  #pragma unroll
  for (int i = 0; i < 4; ++i) acc[i] = (f32x4){0.f, 0.f, 0.f, 0.f};

  if (wpack) {
    const unsigned short* Bq = wpack + (size_t)(col0 + l15) * FEATD + quad * 8;
    for (int k = 0; k < FEATD; k += 32) {
      const bf16x8 a  = load8cvt(Ap + k);
      const bf16x8 b0 = *(const bf16x8*)(Bq + k);
      const bf16x8 b1 = *(const bf16x8*)(Bq + (size_t)16 * FEATD + k);
      const bf16x8 b2 = *(const bf16x8*)(Bq + (size_t)32 * FEATD + k);
      const bf16x8 b3 = *(const bf16x8*)(Bq + (size_t)48 * FEATD + k);
      acc[0] = __builtin_amdgcn_mfma_f32_16x16x32_bf16(a, b0, acc[0], 0, 0, 0);
      acc[1] = __builtin_amdgcn_mfma_f32_16x16x32_bf16(a, b1, acc[1], 0, 0, 0);
      acc[2] = __builtin_amdgcn_mfma_f32_16x16x32_bf16(a, b2, acc[2], 0, 0, 0);
      acc[3] = __builtin_amdgcn_mfma_f32_16x16x32_bf16(a, b3, acc[3], 0, 0, 0);
    }
  } else {
    const float* Bp = B + (size_t)(col0 + l15) * FEATD + quad * 8;
    for (int k = 0; k < FEATD; k += 32) {
      const bf16x8 a  = load8cvt(Ap + k);
      const bf16x8 b0 = load8cvt(Bp + k);
      const bf16x8 b1 = load8cvt(Bp + (size_t)16 * FEATD + k);
      const bf16x8 b2 = load8cvt(Bp + (size_t)32 * FEATD + k);
      const bf16x8 b3 = load8cvt(Bp + (size_t)48 * FEATD + k);
      acc[0] = __builtin_amdgcn_mfma_f32_16x16x32_bf16(a, b0, acc[0], 0, 0, 0);
      acc[1] = __builtin_amdgcn_mfma_f32_16x16x32_bf16(a, b1, acc[1], 0, 0, 0);
      acc[2] = __builtin_amdgcn_mfma_f32_16x16x32_bf16(a, b2, acc[2], 0, 0, 0);
      acc[3] = __builtin_amdgcn_mfma_f32_16x16x32_bf16(a, b3, acc[3], 0, 0, 0);
    }
  }

  #pragma unroll
  for (int ct = 0; ct < 4; ++ct) {
    const int n = col0 + ct * 16 + l15;
    const float bn = bias[n];
    #pragma unroll
    for (int r = 0; r < 4; ++r) {
      const int mm = row0 + quad * 4 + r;
      const float v = acc[ct][r] + bn;
      if (apack) apack[(size_t)mm * TFDIM + n] = bfbits(v);
      else       stage[(size_t)mm * LDO + n] = v;
    }
  }
}

// ---------------------------------------------------------------------------
// K2 — fused projections, 16 rows/block, 128 threads (t = HID column).
// which==0: h_src -> DENSE hpack (ws) or f32 cols[256,512) (fallback)
// which==1: g_dst -> f32 cols[512,768) (always; attn reads it)
// grid = 2048: b = rb | h<<9 | which<<10
// ---------------------------------------------------------------------------
__global__ __launch_bounds__(128) void proj_all(
    const float* __restrict__ emb_src, const float* __restrict__ emb_dest,
    const float* __restrict__ att_W, const float* __restrict__ att_W2,
    float* __restrict__ stage, unsigned short* __restrict__ hpack)
{
  const int t = threadIdx.x;
  const int b = blockIdx.x;
  const int rb    = b & 511;
  const int h     = (b >> 9) & 1;
  const int which = b >> 10;
  const int row0  = rb * 16;

  __shared__ float se[16][EMBD];
  __shared__ float hh[16][HIDD];

  const float* e = (which ? emb_dest : emb_src) + (size_t)row0 * EMBD;
  for (int i = t; i < 16 * EMBD; i += 128) se[i >> 6][i & 63] = e[i];
  __syncthreads();

  float acc[16];
  #pragma unroll
  for (int r = 0; r < 16; ++r) acc[r] = 0.f;
  const float* W = att_W + (size_t)h * EMBD * HIDD + t;
  for (int d = 0; d < EMBD; ++d) {
    const float w = W[d * HIDD];
    #pragma unroll
    for (int r = 0; r < 16; ++r) acc[r] += se[r][d] * w;
  }

  if (!which) {
    #pragma unroll
    for (int r = 0; r < 16; ++r) {
      const size_t row = row0 + r;
      if (hpack) hpack[row * TFDIM + h * HIDD + t] = bfbits(acc[r]);
      else       stage[row * LDO + 256 + h * HIDD + t] = acc[r];
    }
    return;
  }

  #pragma unroll
  for (int r = 0; r < 16; ++r) hh[r][t] = acc[r];
  __syncthreads();

  float g[16];
  #pragma unroll
  for (int r = 0; r < 16; ++r) g[r] = 0.f;
  const float* W2 = att_W2 + (size_t)h * HIDD * HIDD + t;
  for (int d = 0; d < HIDD; ++d) {
    const float w2 = W2[d * HIDD];
    #pragma unroll
    for (int r = 0; r < 16; ++r) g[r] += hh[r][d] * w2;
  }
  #pragma unroll
  for (int r = 0; r < 16; ++r)
    stage[(size_t)(row0 + r) * LDO + 512 + h * HIDD + t] = g[r];
}

// ---------------------------------------------------------------------------
// K4 — WAVE-AUTONOMOUS attention (R10): one wave per dest row, ZERO
// __syncthreads. R9's measurement: attn stuck ~150us even with 16x less
// traffic -> not BW-bound; the last unablated structure is the 4-wave
// barrier-synced block (12 barriers, worst-wave herding). Here each wave
// privately: streams its bias row (coalesced) + ballot-rank compaction
// (no atomics — running uniform offset), scores 16 nbrs/round (4-lane
// groups, shuffle-only), wave-shuffle softmax, coalesced row-walk accum.
// 8192 independent wave-pipelines. LDS partitioned per wave. Dense path
// (count==0 or >SCAP, never taken at 1%): per-wave online softmax over
// hpack/apack + bias mask — count==0 degenerates to uniform mean exactly.
// ---------------------------------------------------------------------------
__global__ __launch_bounds__(256, 6) void attn_wave(
    const float* __restrict__ bias, const float* __restrict__ stage,
    const unsigned short* __restrict__ hpack,
    const unsigned short* __restrict__ apack,
    float* __restrict__ out)
{
  const int wv = threadIdx.x >> 6, lane = threadIdx.x & 63;
  const int m = blockIdx.x * 4 + wv;

  __shared__ float gq[4][4][68];   // [wave][slice][64+pad] g broadcasts
  __shared__ float s0[4][256], s1[4][256];
  __shared__ int   lidx[4][256];

  // ---- g load: lane covers 4 consecutive of g_dst row (256 f32) ----
  // gs layout: h0[0..127], h1[0..127]; slice q = idx>>6, elem = idx&63.
  const float* gs = stage + (size_t)m * LDO + 512;
  {
    const f32x4 gv = *(const f32x4*)(gs + lane * 4);
    #pragma unroll
    for (int i = 0; i < 4; ++i) {
      const int idx = lane * 4 + i;
      gq[wv][idx >> 6][idx & 63] = gv[i];
    }
  }

  // ---- extraction: coalesced bias stream + ballot-rank (no atomics) ----
  const float* brow = bias + (size_t)m * N_SRC;
  int off = 0;
  for (int r = 0; r < 32; ++r) {
    const f32x4 v = *(const f32x4*)(brow + r * 256 + lane * 4);
    #pragma unroll
    for (int e = 0; e < 4; ++e) {
      const bool nz = v[e] > 0.f;
      const unsigned long long msk = __ballot(nz);
      if (nz) {
        const int p = off + __popcll(msk & ((1ull << lane) - 1ull));
        if (p < 256) lidx[wv][p] = r * 256 + lane * 4 + e;
      }
      off += __popcll(msk);
    }
  }
  const int count = off;   // uniform across the wave

  if (count > 0 && count <= SCAP) {
    const int countPad = (count + 3) & ~3;
    if (lane < countPad - count) lidx[wv][count + lane] = 0;

    // ---- scores: 4 lanes per neighbor (r4 = h*2+half), 16 nbrs/round ----
    const int grp = lane >> 2, r4 = lane & 3;
    const int h = r4 >> 1, half = r4 & 1;
    const float* gh = gq[wv][r4];
    for (int t0 = 0; t0 < count; t0 += 16) {
      const int t = t0 + grp;
      float q = 0.f;
      if (t < count) {
        const int j = lidx[wv][t];
        const __bf16* hb =
            (const __bf16*)hpack + (size_t)j * TFDIM + h * HIDD + half * 64;
        #pragma unroll
        for (int s = 0; s < 8; ++s) {
          const bf16x8 x = *(const bf16x8*)(hb + s * 8);
          #pragma unroll
          for (int e = 0; e < 8; ++e) q += gh[s * 8 + e] * (float)x[e];
        }
      }
      q += __shfl_xor(q, 1);  // combine the two col-halves of this head
      if (t < count && half == 0) {
        const float sc = (q > 0.f) ? q : expm1f(q);   // elu, alpha=1
        if (h == 0) s0[wv][t] = sc; else s1[wv][t] = sc;
      }
    }

    // ---- wave max over s0/s1[0,count) ----
    float m0 = -3.4e38f, m1 = -3.4e38f;
    for (int t = lane; t < count; t += 64) {
      m0 = fmaxf(m0, s0[wv][t]);
      m1 = fmaxf(m1, s1[wv][t]);
    }
    #pragma unroll
    for (int o = 32; o; o >>= 1) {
      m0 = fmaxf(m0, __shfl_xor(m0, o));
      m1 = fmaxf(m1, __shfl_xor(m1, o));
    }

    // ---- exp + wave sum; zero the pad entries ----
    float l0 = 0.f, l1 = 0.f;
    for (int t = lane; t < countPad; t += 64) {
      float w0 = 0.f, w1 = 0.f;
      if (t < count) {
        w0 = __expf(s0[wv][t] - m0);
        w1 = __expf(s1[wv][t] - m1);
      }
      s0[wv][t] = w0; s1[wv][t] = w1;
      l0 += w0; l1 += w1;
    }
    #pragma unroll
    for (int o = 32; o; o >>= 1) {
      l0 += __shfl_xor(l0, o);
      l1 += __shfl_xor(l1, o);
    }

    // ---- accumulation: coalesced 512B row walk, 4-wide unroll ----
    float b0[4] = {0.f, 0.f, 0.f, 0.f};
    float b1[4] = {0.f, 0.f, 0.f, 0.f};
    const int c4 = lane << 2;
    for (int t = 0; t < countPad; t += 4) {
      #pragma unroll
      for (int q = 0; q < 4; ++q) {
        const int j = lidx[wv][t + q];
        const float u0 = s0[wv][t + q], u1 = s1[wv][t + q];
        const u16x4 tv = *(const u16x4*)(apack + (size_t)j * TFDIM + c4);
        #pragma unroll
        for (int i = 0; i < 4; ++i) {
          const float f = bf2f(tv[i]);
          b0[i] += u0 * f;
          b1[i] += u1 * f;
        }
      }
    }
    float* orow = out + (size_t)m * TFDIM + c4;
    #pragma unroll
    for (int i = 0; i < 4; ++i)
      orow[i] = 0.5f * (b0[i] / l0 + b1[i] / l1);
    return;
  }

  // ---- dense exact path (never taken at 1%; count==0 -> uniform mean) ----
  float M0 = -3.4e38f, M1 = -3.4e38f, L0 = 0.f, L1 = 0.f;
  float a0[4] = {0.f, 0.f, 0.f, 0.f};
  float a1[4] = {0.f, 0.f, 0.f, 0.f};
  const int c4 = lane << 2;
  for (int j0 = 0; j0 < N_SRC; j0 += 64) {
    const int j = j0 + lane;
    const __bf16* hb = (const __bf16*)hpack + (size_t)j * TFDIM;
    float q0 = 0.f, q1 = 0.f;
    #pragma unroll
    for (int s = 0; s < 16; ++s) {
      const bf16x8 x = *(const bf16x8*)(hb + s * 8);
      const bf16x8 y = *(const bf16x8*)(hb + HIDD + s * 8);
      #pragma unroll
      for (int e = 0; e < 8; ++e) {
        const int d = s * 8 + e;
        q0 += gq[wv][d >> 6][d & 63] * (float)x[e];
        q1 += gq[wv][2 + (d >> 6)][d & 63] * (float)y[e];
      }
    }
    const bool nz = brow[j] > 0.f;
    const float sc0 = nz ? ((q0 > 0.f) ? q0 : expm1f(q0)) : -9e15f;
    const float sc1 = nz ? ((q1 > 0.f) ? q1 : expm1f(q1)) : -9e15f;

    float cm0 = sc0, cm1 = sc1;
    #pragma unroll
    for (int o = 32; o; o >>= 1) {
      cm0 = fmaxf(cm0, __shfl_xor(cm0, o));
      cm1 = fmaxf(cm1, __shfl_xor(cm1, o));
    }
    const float nM0 = fmaxf(M0, cm0), nM1 = fmaxf(M1, cm1);
    const float r0 = __expf(M0 - nM0), r1 = __expf(M1 - nM1);
    const float w0 = __expf(sc0 - nM0), w1 = __expf(sc1 - nM1);
    s0[wv][lane] = w0; s1[wv][lane] = w1;
    float cl0 = w0, cl1 = w1;
    #pragma unroll
    for (int o = 32; o; o >>= 1) {
      cl0 += __shfl_xor(cl0, o);
      cl1 += __shfl_xor(cl1, o);
    }
    L0 = L0 * r0 + cl0;  L1 = L1 * r1 + cl1;
    M0 = nM0; M1 = nM1;
    #pragma unroll
    for (int i = 0; i < 4; ++i) { a0[i] *= r0; a1[i] *= r1; }
    for (int n = 0; n < 64; ++n) {
      const float u0 = s0[wv][n], u1 = s1[wv][n];
      const u16x4 tv = *(const u16x4*)(apack + (size_t)(j0 + n) * TFDIM + c4);
      #pragma unroll
      for (int i = 0; i < 4; ++i) {
        const float f = bf2f(tv[i]);
        a0[i] += u0 * f;
        a1[i] += u1 * f;
      }
    }
  }
  float* orow = out + (size_t)m * TFDIM + c4;
  #pragma unroll
  for (int i = 0; i < 4; ++i)
    orow[i] = 0.5f * (a0[i] / L0 + a1[i] / L1);
}

// ---------------------------------------------------------------------------
// K4-fallback (ws too small) — proven streaming attention, unchanged.
// Uses only f32 stage regions + raw bias (no ws).
// ---------------------------------------------------------------------------
__global__ __launch_bounds__(64) void attn_stream(
    const float* __restrict__ bias, const float* __restrict__ stage,
    float* __restrict__ out)
{
  const int lane = threadIdx.x;
  const int m = blockIdx.x;
  const int c0 = lane * 4;

  __shared__ float g0[HIDD], g1[HIDD];
  __shared__ int   ring[256];
  __shared__ float wb0[64], wb1[64];

  const float* gs = stage + (size_t)m * LDO + 512;
  g0[lane]      = gs[lane];
  g0[lane + 64] = gs[lane + 64];
  g1[lane]      = gs[HIDD + lane];
  g1[lane + 64] = gs[HIDD + lane + 64];
  __syncthreads();

  float O0[4] = {0.f, 0.f, 0.f, 0.f};
  float O1[4] = {0.f, 0.f, 0.f, 0.f};
  float M0 = -3.4e38f, M1 = -3.4e38f;
  float L0 = 0.f, L1 = 0.f;

  auto flush = [&](int b, int rp) {
    __syncthreads();
    int j = -1;
    if (lane < b) j = ring[(rp + lane) & 255];
    float s0 = 0.f, s1 = 0.f;
    if (j >= 0) {
      const float* h0 = stage + (size_t)j * LDO + 256;
      const float* h1 = h0 + HIDD;
      #pragma unroll
      for (int d = 0; d < HIDD; d += 4) {
        const f32x4 a = *(const f32x4*)(h0 + d);
        const f32x4 c = *(const f32x4*)(h1 + d);
        #pragma unroll
        for (int e = 0; e < 4; ++e) {
          s0 += g0[d + e] * a[e];
          s1 += g1[d + e] * c[e];
        }
      }
      s0 = (s0 > 0.f) ? s0 : expm1f(s0);
      s1 = (s1 > 0.f) ? s1 : expm1f(s1);
    }
    float m0 = (j >= 0) ? s0 : -3.4e38f;
    float m1 = (j >= 0) ? s1 : -3.4e38f;
    #pragma unroll
    for (int off = 32; off; off >>= 1) {
      m0 = fmaxf(m0, __shfl_xor(m0, off));
      m1 = fmaxf(m1, __shfl_xor(m1, off));
    }
    const float nM0 = fmaxf(M0, m0), nM1 = fmaxf(M1, m1);
    const float w0 = (j >= 0) ? __expf(s0 - nM0) : 0.f;
    const float w1 = (j >= 0) ? __expf(s1 - nM1) : 0.f;
    float l0 = w0, l1 = w1;
    #pragma unroll
    for (int off = 32; off; off >>= 1) {
      l0 += __shfl_xor(l0, off);
      l1 += __shfl_xor(l1, off);
    }
    const float r0 = __expf(M0 - nM0);
    const float r1 = __expf(M1 - nM1);
    L0 = L0 * r0 + l0;  L1 = L1 * r1 + l1;
    M0 = nM0;  M1 = nM1;
    #pragma unroll
    for (int i = 0; i < 4; ++i) { O0[i] *= r0; O1[i] *= r1; }
    wb0[lane] = w0;  wb1[lane] = w1;
    __syncthreads();
    for (int n = 0; n < b; ++n) {
      const int jj = ring[(rp + n) & 255];
      const float wa = wb0[n], wc = wb1[n];
      const f32x4 tv = *(const f32x4*)(stage + (size_t)jj * LDO + c0);
      #pragma unroll
      for (int i = 0; i < 4; ++i) {
        O0[i] += wa * tv[i];
        O1[i] += wc * tv[i];
      }
    }
    __syncthreads();
  };

  const float* brow = bias + (size_t)m * N_SRC;
  int wpos = 0, rpos = 0;
  for (int base = 0; base < N_SRC; base += 256) {
    const f32x4 v = *(const f32x4*)(brow + base + lane * 4);
    #pragma unroll
    for (int e = 0; e < 4; ++e) {
      const bool nz = v[e] > 0.f;
      const unsigned long long mask = __ballot(nz);
      if (nz) {
        const int pos = wpos + __popcll(mask & ((1ull << lane) - 1ull));
        ring[pos & 255] = base + lane * 4 + e;
      }
      wpos += __popcll(mask);
      if (wpos - rpos >= 64) { flush(64, rpos); rpos += 64; }
    }
  }
  while (wpos - rpos > 0) {
    const int b = (wpos - rpos < 64) ? (wpos - rpos) : 64;
    flush(b, rpos);
    rpos += b;
  }

  float* orow = out + (size_t)m * TFDIM + c0;
  if (wpos == 0) {
    float o[4] = {0.f, 0.f, 0.f, 0.f};
    for (int j = 0; j < N_SRC; ++j) {
      const f32x4 tv = *(const f32x4*)(stage + (size_t)j * LDO + c0);
      #pragma unroll
      for (int i = 0; i < 4; ++i) o[i] += tv[i];
    }
    const float inv = 1.f / (float)N_SRC;
    #pragma unroll
    for (int i = 0; i < 4; ++i) orow[i] = o[i] * inv;
  } else {
    const float i0 = 1.f / L0, i1 = 1.f / L1;
    #pragma unroll
    for (int i = 0; i < 4; ++i)
      orow[i] = 0.5f * (O0[i] * i0 + O1[i] * i1);
  }
}

// ---------------------------------------------------------------------------
// K3 — decoder GEMM v2 (ws path): feature_hat = transformed @ dec_W^T + dec_b.
// A from ws bf16 pack; B from bf16 dpack. 64x64 tiles, grid (128,16).
// ---------------------------------------------------------------------------
__global__ __launch_bounds__(256) void gemm_mfma_dec2(
    const unsigned short* __restrict__ apack,  // [8192][256] bf16 bits
    const unsigned short* __restrict__ dpack,  // dec_W [1024][256] bf16 bits
    const float* __restrict__ bias,            // dec_b [1024]
    float* __restrict__ OUT)                   // out1 [8192][1024] f32
{
  const int wave = threadIdx.x >> 6, lane = threadIdx.x & 63;
  const int l15 = lane & 15, quad = lane >> 4;
  const int row0 = blockIdx.x * 64 + wave * 16;
  const int col0 = blockIdx.y * 64;

  const unsigned short* Ap = apack + (size_t)(row0 + l15) * TFDIM + quad * 8;
  const unsigned short* Bp = dpack + (size_t)(col0 + l15) * TFDIM + quad * 8;

  f32x4 acc[4];
  #pragma unroll
  for (int i = 0; i < 4; ++i) acc[i] = (f32x4){0.f, 0.f, 0.f, 0.f};

  #pragma unroll
  for (int k = 0; k < TFDIM; k += 32) {
    const bf16x8 a  = *(const bf16x8*)(Ap + k);
    const bf16x8 b0 = *(const bf16x8*)(Bp + k);
    const bf16x8 b1 = *(const bf16x8*)(Bp + (size_t)16 * TFDIM + k);
    const bf16x8 b2 = *(const bf16x8*)(Bp + (size_t)32 * TFDIM + k);
    const bf16x8 b3 = *(const bf16x8*)(Bp + (size_t)48 * TFDIM + k);
    acc[0] = __builtin_amdgcn_mfma_f32_16x16x32_bf16(a, b0, acc[0], 0, 0, 0);
    acc[1] = __builtin_amdgcn_mfma_f32_16x16x32_bf16(a, b1, acc[1], 0, 0, 0);
    acc[2] = __builtin_amdgcn_mfma_f32_16x16x32_bf16(a, b2, acc[2], 0, 0, 0);
    acc[3] = __builtin_amdgcn_mfma_f32_16x16x32_bf16(a, b3, acc[3], 0, 0, 0);
  }

  #pragma unroll
  for (int ct = 0; ct < 4; ++ct) {
    const int n = col0 + ct * 16 + l15;
    const float bn = bias[n];
    #pragma unroll
    for (int r = 0; r < 4; ++r) {
      const int mm = row0 + quad * 4 + r;
      OUT[(size_t)mm * LDO + n] = acc[ct][r] + bn;
    }
  }
}

// ---------------------------------------------------------------------------
// K3-fallback (ws too small) — in-place decoder GEMM, runs LAST.
// ---------------------------------------------------------------------------
__global__ __launch_bounds__(128) void gemm_mfma_dec(
    const float* __restrict__ W,     // dec_W [1024][256]
    const float* __restrict__ bias,  // dec_b [1024]
    float* __restrict__ OUT)         // out1 [8192][1024] f32
{
  const int row0 = blockIdx.x * 32;
  const int tid = threadIdx.x;
  const int wave = tid >> 6, lane = tid & 63;
  const int l15 = lane & 15, quad = lane >> 4;

  __shared__ __bf16 Ab[32][TFDIM + 8];   // +8 bf16 pad (16 B)

  for (int i = tid; i < 32 * TFDIM; i += 128) {
    const int r = i >> 8, k = i & 255;
    Ab[r][k] = (__bf16)OUT[(size_t)(row0 + r) * LDO + k];
  }
  __syncthreads();

  bf16x8 af[8];
  #pragma unroll
  for (int ks = 0; ks < 8; ++ks)
    af[ks] = *(const bf16x8*)&Ab[wave * 16 + l15][ks * 32 + quad * 8];

  for (int ct = 0; ct < 16; ++ct) {
    f32x4 acc[4];
    #pragma unroll
    for (int i = 0; i < 4; ++i) acc[i] = (f32x4){0.f, 0.f, 0.f, 0.f};
    #pragma unroll
    for (int ks = 0; ks < 8; ++ks) {
      #pragma unroll
      for (int cg = 0; cg < 4; ++cg) {
        const int n = ct * 64 + cg * 16 + l15;
        const bf16x8 bf = load8cvt(W + (size_t)n * TFDIM + ks * 32 + quad * 8);
        acc[cg] = __builtin_amdgcn_mfma_f32_16x16x32_bf16(af[ks], bf, acc[cg], 0, 0, 0);
      }
    }
    #pragma unroll
    for (int cg = 0; cg < 4; ++cg) {
      const int n = ct * 64 + cg * 16 + l15;
      const float bn = bias[n];
      #pragma unroll
      for (int r = 0; r < 4; ++r) {
        const int mm = row0 + wave * 16 + quad * 4 + r;
        OUT[(size_t)mm * LDO + n] = acc[cg][r] + bn;
      }
    }
  }
}

// ---------------------------------------------------------------------------
extern "C" void kernel_launch(void* const* d_in, const int* in_sizes, int n_in,
                              void* d_out, int out_size, void* d_ws, size_t ws_size,
                              hipStream_t stream) {
  const float* bias        = (const float*)d_in[0];
  const float* emb_dest    = (const float*)d_in[1];
  const float* emb_src     = (const float*)d_in[2];
  const float* feature_src = (const float*)d_in[3];
  const float* fc_W        = (const float*)d_in[4];
  const float* fc_b        = (const float*)d_in[5];
  const float* dec_W       = (const float*)d_in[6];
  const float* dec_b       = (const float*)d_in[7];
  const float* att_W       = (const float*)d_in[8];
  const float* att_W2      = (const float*)d_in[9];

  float* out0 = (float*)d_out;                  // feature_src_re [8192][256]
  float* out1 = out0 + (size_t)N_DEST * TFDIM;  // feature_hat   [8192][1024]

  // ws layout: apack 4 MiB | wpack 512 KiB | dpack 512 KiB | hpack 4 MiB
  const size_t apack_bytes = (size_t)N_SRC * TFDIM * sizeof(unsigned short);
  const size_t wpack_bytes = (size_t)TFDIM * FEATD * sizeof(unsigned short);
  const size_t dpack_bytes = (size_t)FEATD * TFDIM * sizeof(unsigned short);
  const size_t hpack_bytes = (size_t)N_SRC * TFDIM * sizeof(unsigned short);
  const bool use_ws =
      (ws_size >= apack_bytes + wpack_bytes + dpack_bytes + hpack_bytes);
  unsigned short* apack = (unsigned short*)d_ws;
  unsigned short* wpack = (unsigned short*)((char*)d_ws + apack_bytes);
  unsigned short* dpack = (unsigned short*)((char*)wpack + wpack_bytes);
  unsigned short* hpack = (unsigned short*)((char*)dpack + dpack_bytes);

  // K0: one-shot weight bf16 conversion
  if (use_ws)
    cvt_weights<<<512, 256, 0, stream>>>(fc_W, dec_W, wpack, dpack);

  // K1: transformed -> dense apack (ws) or f32 stage (fallback)
  {
    dim3 grid(N_SRC / 64, TFDIM / 64);
    gemm_mfma_k1<<<grid, 256, 0, stream>>>(
        feature_src, fc_W, fc_b, out1,
        use_ws ? apack : (unsigned short*)nullptr,
        use_ws ? wpack : (const unsigned short*)nullptr);
  }
  // K2: h_src -> dense hpack (ws) or f32 stage; g_dst -> f32 stage (always)
  proj_all<<<2048, 128, 0, stream>>>(emb_src, emb_dest, att_W, att_W2, out1,
                                     use_ws ? hpack : (unsigned short*)nullptr);
  // K4: wave-autonomous attention -> out0
  if (use_ws) {
    attn_wave<<<N_DEST / 4, 256, 0, stream>>>(bias, out1, hpack, apack, out0);
  } else {
    attn_stream<<<N_DEST, 64, 0, stream>>>(bias, out1, out0);
  }
  // K3: decoder GEMM, overwrites out1 with feature_hat (LAST)
  if (use_ws) {
    dim3 grid(N_SRC / 64, FEATD / 64);
    gemm_mfma_dec2<<<grid, 256, 0, stream>>>(apack, dpack, dec_b, out1);
  } else {
    gemm_mfma_dec<<<N_SRC / 32, 128, 0, stream>>>(dec_W, dec_b, out1);
  }
}

// Round 12
// 627.570 us; speedup vs baseline: 1.0767x; 1.0767x over previous
//
#include <hip/hip_runtime.h>
#include <hip/hip_bf16.h>

#define N_DEST 8192
#define N_SRC  8192
#define FEATD  1024
#define TFDIM  256
#define EMBD   64
#define HIDD   128
#define LDO    1024   // out1 row stride (f32). Staging inside out1 rows:
                      // [0,256)   transformed f32          [dense path]
                      // [256,512) h_src f32 (h0,h1)        [dense/fallback]
                      // [512,768) g_dst f32 (h0,h1)
#define SCAP 240      // fast-path capacity (count>SCAP -> dense path)

typedef float  f32x4  __attribute__((ext_vector_type(4)));
typedef __bf16 bf16x8 __attribute__((ext_vector_type(8)));
typedef unsigned short u16x4 __attribute__((ext_vector_type(4)));

__device__ inline bf16x8 load8cvt(const float* p) {
  const f32x4 u = *(const f32x4*)p;
  const f32x4 v = *(const f32x4*)(p + 4);
  bf16x8 r;
  #pragma unroll
  for (int i = 0; i < 4; ++i) { r[i] = (__bf16)u[i]; r[i + 4] = (__bf16)v[i]; }
  return r;
}
__device__ inline unsigned short bfbits(float f) {
  __bf16 b = (__bf16)f;
  return *(unsigned short*)&b;
}
__device__ inline float bf2f(unsigned short u) {
  union { unsigned int i; float f; } x;
  x.i = (unsigned int)u << 16;
  return x.f;
}

// ---------------------------------------------------------------------------
// K0 — one-shot weight conversion: fc_W and dec_W f32 -> bf16 bits in ws.
// ---------------------------------------------------------------------------
__global__ __launch_bounds__(256) void cvt_weights(
    const float* __restrict__ fc_W, const float* __restrict__ dec_W,
    unsigned short* __restrict__ wpack, unsigned short* __restrict__ dpack)
{
  const int which = blockIdx.x >> 8;  // 0: fc_W, 1: dec_W (both 262144 elems)
  const int i = ((blockIdx.x & 255) * 256 + threadIdx.x) * 4;
  const float* src = which ? dec_W : fc_W;
  unsigned short* dst = which ? dpack : wpack;
  const f32x4 v = *(const f32x4*)(src + i);
  u16x4 o;
  #pragma unroll
  for (int e = 0; e < 4; ++e) o[e] = bfbits(v[e]);
  *(u16x4*)(dst + i) = o;
}

// ---------------------------------------------------------------------------
// K1 — MFMA GEMM: transformed = feature_src @ fc_W^T + fc_b.
// 64x64 tile, 4 waves. A: f32 loads -> bf16 cvt. B: direct bf16 from wpack
// (ws path) or f32+cvt (fallback). Writes: f32 stage + DENSE apack.
// ---------------------------------------------------------------------------
__global__ __launch_bounds__(256) void gemm_mfma_k1(
    const float* __restrict__ A, const float* __restrict__ B,
    const float* __restrict__ bias, float* __restrict__ stage,
    unsigned short* __restrict__ apack,
    const unsigned short* __restrict__ wpack)
{
  const int wave = threadIdx.x >> 6, lane = threadIdx.x & 63;
  const int l15 = lane & 15, quad = lane >> 4;
  const int row0 = blockIdx.x * 64 + wave * 16;
  const int col0 = blockIdx.y * 64;

  const float* Ap = A + (size_t)(row0 + l15) * FEATD + quad * 8;

  f32x4 acc[4];
  #pragma unroll
  for (int i = 0; i < 4; ++i) acc[i] = (f32x4){0.f, 0.f, 0.f, 0.f};

  if (wpack) {
    const unsigned short* Bq = wpack + (size_t)(col0 + l15) * FEATD + quad * 8;
    for (int k = 0; k < FEATD; k += 32) {
      const bf16x8 a  = load8cvt(Ap + k);
      const bf16x8 b0 = *(const bf16x8*)(Bq + k);
      const bf16x8 b1 = *(const bf16x8*)(Bq + (size_t)16 * FEATD + k);
      const bf16x8 b2 = *(const bf16x8*)(Bq + (size_t)32 * FEATD + k);
      const bf16x8 b3 = *(const bf16x8*)(Bq + (size_t)48 * FEATD + k);
      acc[0] = __builtin_amdgcn_mfma_f32_16x16x32_bf16(a, b0, acc[0], 0, 0, 0);
      acc[1] = __builtin_amdgcn_mfma_f32_16x16x32_bf16(a, b1, acc[1], 0, 0, 0);
      acc[2] = __builtin_amdgcn_mfma_f32_16x16x32_bf16(a, b2, acc[2], 0, 0, 0);
      acc[3] = __builtin_amdgcn_mfma_f32_16x16x32_bf16(a, b3, acc[3], 0, 0, 0);
    }
  } else {
    const float* Bp = B + (size_t)(col0 + l15) * FEATD + quad * 8;
    for (int k = 0; k < FEATD; k += 32) {
      const bf16x8 a  = load8cvt(Ap + k);
      const bf16x8 b0 = load8cvt(Bp + k);
      const bf16x8 b1 = load8cvt(Bp + (size_t)16 * FEATD + k);
      const bf16x8 b2 = load8cvt(Bp + (size_t)32 * FEATD + k);
      const bf16x8 b3 = load8cvt(Bp + (size_t)48 * FEATD + k);
      acc[0] = __builtin_amdgcn_mfma_f32_16x16x32_bf16(a, b0, acc[0], 0, 0, 0);
      acc[1] = __builtin_amdgcn_mfma_f32_16x16x32_bf16(a, b1, acc[1], 0, 0, 0);
      acc[2] = __builtin_amdgcn_mfma_f32_16x16x32_bf16(a, b2, acc[2], 0, 0, 0);
      acc[3] = __builtin_amdgcn_mfma_f32_16x16x32_bf16(a, b3, acc[3], 0, 0, 0);
    }
  }

  #pragma unroll
  for (int ct = 0; ct < 4; ++ct) {
    const int n = col0 + ct * 16 + l15;
    const float bn = bias[n];
    #pragma unroll
    for (int r = 0; r < 4; ++r) {
      const int mm = row0 + quad * 4 + r;
      const float v = acc[ct][r] + bn;
      stage[(size_t)mm * LDO + n] = v;
      if (apack) apack[(size_t)mm * TFDIM + n] = bfbits(v);
    }
  }
}

// ---------------------------------------------------------------------------
// K2 — fused projections, 16 rows/block, 128 threads (t = HID column).
// which==0: h_src -> f32 cols[256,512) + DENSE hpack (bf16, ws)
// which==1: g_dst -> f32 cols[512,768)
// grid = 2048: b = rb | h<<9 | which<<10
// ---------------------------------------------------------------------------
__global__ __launch_bounds__(128) void proj_all(
    const float* __restrict__ emb_src, const float* __restrict__ emb_dest,
    const float* __restrict__ att_W, const float* __restrict__ att_W2,
    float* __restrict__ stage, unsigned short* __restrict__ hpack)
{
  const int t = threadIdx.x;
  const int b = blockIdx.x;
  const int rb    = b & 511;
  const int h     = (b >> 9) & 1;
  const int which = b >> 10;
  const int row0  = rb * 16;

  __shared__ float se[16][EMBD];
  __shared__ float hh[16][HIDD];

  const float* e = (which ? emb_dest : emb_src) + (size_t)row0 * EMBD;
  for (int i = t; i < 16 * EMBD; i += 128) se[i >> 6][i & 63] = e[i];
  __syncthreads();

  float acc[16];
  #pragma unroll
  for (int r = 0; r < 16; ++r) acc[r] = 0.f;
  const float* W = att_W + (size_t)h * EMBD * HIDD + t;
  for (int d = 0; d < EMBD; ++d) {
    const float w = W[d * HIDD];
    #pragma unroll
    for (int r = 0; r < 16; ++r) acc[r] += se[r][d] * w;
  }

  if (!which) {
    #pragma unroll
    for (int r = 0; r < 16; ++r) {
      const size_t row = row0 + r;
      stage[row * LDO + 256 + h * HIDD + t] = acc[r];
      if (hpack) hpack[row * TFDIM + h * HIDD + t] = bfbits(acc[r]);
    }
    return;
  }

  #pragma unroll
  for (int r = 0; r < 16; ++r) hh[r][t] = acc[r];
  __syncthreads();

  float g[16];
  #pragma unroll
  for (int r = 0; r < 16; ++r) g[r] = 0.f;
  const float* W2 = att_W2 + (size_t)h * HIDD * HIDD + t;
  for (int d = 0; d < HIDD; ++d) {
    const float w2 = W2[d * HIDD];
    #pragma unroll
    for (int r = 0; r < 16; ++r) g[r] += hh[r][d] * w2;
  }
  #pragma unroll
  for (int r = 0; r < 16; ++r)
    stage[(size_t)(row0 + r) * LDO + 512 + h * HIDD + t] = g[r];
}

// ---------------------------------------------------------------------------
// K4 — FUSED extraction + gather attention. CHAMPION STRUCTURE (R8, 177us):
// ballot+atomic extraction, gq[4][68] bank-spread, (256,6), dense packs.
// R11 isolated change: the bias stream uses NON-TEMPORAL loads. Mechanism
// (from R9's measurement: removing the stream dropped FETCH 256MB but attn
// only -24us; R10: fewer bytes, slower): the 256MB/dispatch bias stream
// continuously flushes the 256MB L3, so the ~137MB of scattered hpack/apack
// reads miss to HBM (~900cy) instead of hitting L3/L2 (~200cy). NT loads
// stream bias AROUND the caches -> packs stay L3-resident -> scattered
// reads become cache hits. Zero extra kernels, zero extra bytes.
// ---------------------------------------------------------------------------
__global__ __launch_bounds__(256, 6) void attn_fused(
    const float* __restrict__ bias, const float* __restrict__ stage,
    const unsigned short* __restrict__ hpack,
    const unsigned short* __restrict__ apack,
    float* __restrict__ out)
{
  const int m = blockIdx.x;
  const int tid = threadIdx.x;
  const int lane = tid & 63, wv = tid >> 6;

  __shared__ float gq[4][68];   // slice q = h*2+half, padded (bank-spread)
  __shared__ float s0[256], s1[256];
  __shared__ int   lidx[256];
  __shared__ float rA[4], rB[4];
  __shared__ float p0[4][TFDIM], p1[4][TFDIM];  // cross-wave partials (8 KB)
  __shared__ int   cnt;

  // g load: thread tid -> slice wv, elem lane. slice q covers
  // gs[(q>>1)*HIDD + (q&1)*64 + lane]
  const float* gs = stage + (size_t)m * LDO + 512;
  gq[wv][lane] = gs[(wv >> 1) * HIDD + (wv & 1) * 64 + lane];
  if (tid == 0) cnt = 0;
  __syncthreads();

  // ---- inline neighbor extraction: NT bias stream + ballot compaction ----
  const float* brow = bias + (size_t)m * N_SRC;
  for (int base = tid * 4; base < N_SRC; base += 1024) {
    const f32x4 v = __builtin_nontemporal_load((const f32x4*)(brow + base));
    #pragma unroll
    for (int e = 0; e < 4; ++e) {
      const bool nz = v[e] > 0.f;
      const unsigned long long msk = __ballot(nz);
      int wbase = 0;
      if (lane == 0 && msk) wbase = atomicAdd(&cnt, __popcll(msk));
      wbase = __shfl(wbase, 0);
      if (nz) {
        const int p = wbase + __popcll(msk & ((1ull << lane) - 1ull));
        if (p < 256) lidx[p] = base + e;
      }
    }
  }
  __syncthreads();
  const int count = cnt;

  if (count > 0 && count <= SCAP) {
    // pad to multiple of 16 with zero-weight entries -> branch-free accum
    const int countPad = (count + 15) & ~15;
    if (tid >= count && tid < countPad) lidx[tid] = 0;
    __syncthreads();

    // ---- scores: 4 threads per neighbor (slice r4 = h*2+half), 64/pass ----
    const int grp = tid >> 2, r4 = tid & 3;
    const int h = r4 >> 1, half = r4 & 1;
    const float* gh = gq[r4];
    for (int t0 = 0; t0 < count; t0 += 64) {
      const int t = t0 + grp;
      float q = 0.f;
      if (t < count) {
        const int j = lidx[t];
        const __bf16* hb =
            (const __bf16*)hpack + (size_t)j * TFDIM + h * HIDD + half * 64;
        #pragma unroll
        for (int s = 0; s < 8; ++s) {
          const bf16x8 x = *(const bf16x8*)(hb + s * 8);
          #pragma unroll
          for (int e = 0; e < 8; ++e) q += gh[s * 8 + e] * (float)x[e];
        }
      }
      q += __shfl_xor(q, 1);  // combine the two col-halves of this head
      if (t < count && half == 0) {
        const float sc = (q > 0.f) ? q : expm1f(q);   // elu, alpha=1
        if (h == 0) s0[t] = sc; else s1[t] = sc;
      }
    }
    __syncthreads();

    // ---- block max (one element per thread; count <= SCAP < 256) ----
    float m0 = (tid < count) ? s0[tid] : -3.4e38f;
    float m1 = (tid < count) ? s1[tid] : -3.4e38f;
    #pragma unroll
    for (int o = 32; o; o >>= 1) {
      m0 = fmaxf(m0, __shfl_xor(m0, o));
      m1 = fmaxf(m1, __shfl_xor(m1, o));
    }
    if (lane == 0) { rA[wv] = m0; rB[wv] = m1; }
    __syncthreads();
    const float M0 = fmaxf(fmaxf(rA[0], rA[1]), fmaxf(rA[2], rA[3]));
    const float M1 = fmaxf(fmaxf(rB[0], rB[1]), fmaxf(rB[2], rB[3]));
    __syncthreads();  // done reading rA/rB

    // ---- exp + block sum (one element per thread, pad entries -> 0) ----
    float w0 = 0.f, w1 = 0.f;
    if (tid < count) {
      w0 = __expf(s0[tid] - M0);
      w1 = __expf(s1[tid] - M1);
    }
    if (tid < countPad) { s0[tid] = w0; s1[tid] = w1; }
    float l0 = w0, l1 = w1;
    #pragma unroll
    for (int o = 32; o; o >>= 1) {
      l0 += __shfl_xor(l0, o);
      l1 += __shfl_xor(l1, o);
    }
    if (lane == 0) { rA[wv] = l0; rB[wv] = l1; }
    __syncthreads();
    const float L0 = rA[0] + rA[1] + rA[2] + rA[3];
    const float L1 = rB[0] + rB[1] + rB[2] + rB[3];

    // ---- accumulation: 4-wave parallel, 4-wide unrolled independent loads.
    float b0[4] = {0.f, 0.f, 0.f, 0.f};
    float b1[4] = {0.f, 0.f, 0.f, 0.f};
    const int c4 = lane << 2;
    for (int t = wv << 2; t < countPad; t += 16) {
      #pragma unroll
      for (int q = 0; q < 4; ++q) {
        const int j = lidx[t + q];
        const float u0 = s0[t + q], u1 = s1[t + q];
        const u16x4 tv = *(const u16x4*)(apack + (size_t)j * TFDIM + c4);
        #pragma unroll
        for (int i = 0; i < 4; ++i) {
          const float f = bf2f(tv[i]);
          b0[i] += u0 * f;
          b1[i] += u1 * f;
        }
      }
    }
    #pragma unroll
    for (int i = 0; i < 4; ++i) {
      p0[wv][c4 + i] = b0[i];
      p1[wv][c4 + i] = b1[i];
    }
    __syncthreads();
    const float A0 = p0[0][tid] + p0[1][tid] + p0[2][tid] + p0[3][tid];
    const float A1 = p1[0][tid] + p1[1][tid] + p1[2][tid] + p1[3][tid];
    out[(size_t)m * TFDIM + tid] = 0.5f * (A0 / L0 + A1 / L1);
    return;
  }

  // ---- dense exact path (rare): chunked online softmax over all 8192 ----
  float* w0s = (float*)p0[0];  // alias partial buffer (unused in this path)
  float* w1s = (float*)p0[1];
  const int c = tid;
  float a0 = 0.f, a1 = 0.f;
  float M0 = -3.4e38f, M1 = -3.4e38f, L0 = 0.f, L1 = 0.f;
  for (int j0 = 0; j0 < N_SRC; j0 += 256) {
    const int j = j0 + tid;
    const float* hb = stage + (size_t)j * LDO + 256;
    float q0 = 0.f, q1 = 0.f;
    for (int d = 0; d < HIDD; d += 4) {
      const int hf = d >> 6, dd = d & 63;
      const f32x4 x = *(const f32x4*)(hb + d);
      const f32x4 y = *(const f32x4*)(hb + HIDD + d);
      #pragma unroll
      for (int e = 0; e < 4; ++e) {
        q0 += gq[hf][dd + e] * x[e];
        q1 += gq[2 + hf][dd + e] * y[e];
      }
    }
    const bool nz = bias[(size_t)m * N_SRC + j] > 0.f;
    const float sc0 = nz ? ((q0 > 0.f) ? q0 : expm1f(q0)) : -9e15f;
    const float sc1 = nz ? ((q1 > 0.f) ? q1 : expm1f(q1)) : -9e15f;

    float cm0 = sc0, cm1 = sc1;
    #pragma unroll
    for (int o = 32; o; o >>= 1) {
      cm0 = fmaxf(cm0, __shfl_xor(cm0, o));
      cm1 = fmaxf(cm1, __shfl_xor(cm1, o));
    }
    if (lane == 0) { rA[wv] = cm0; rB[wv] = cm1; }
    __syncthreads();
    const float CM0 = fmaxf(fmaxf(rA[0], rA[1]), fmaxf(rA[2], rA[3]));
    const float CM1 = fmaxf(fmaxf(rB[0], rB[1]), fmaxf(rB[2], rB[3]));
    __syncthreads();  // done reading rA/rB

    const float nM0 = fmaxf(M0, CM0), nM1 = fmaxf(M1, CM1);
    const float r0 = __expf(M0 - nM0), r1 = __expf(M1 - nM1);
    const float w0 = __expf(sc0 - nM0), w1 = __expf(sc1 - nM1);
    w0s[tid] = w0; w1s[tid] = w1;
    float cl0 = w0, cl1 = w1;
    #pragma unroll
    for (int o = 32; o; o >>= 1) {
      cl0 += __shfl_xor(cl0, o);
      cl1 += __shfl_xor(cl1, o);
    }
    if (lane == 0) { rA[wv] = cl0; rB[wv] = cl1; }
    __syncthreads();
    L0 = L0 * r0 + (rA[0] + rA[1] + rA[2] + rA[3]);
    L1 = L1 * r1 + (rB[0] + rB[1] + rB[2] + rB[3]);
    M0 = nM0; M1 = nM1;
    a0 *= r0; a1 *= r1;
    for (int t2 = 0; t2 < 256; ++t2) {
      const float tv = stage[(size_t)(j0 + t2) * LDO + c];
      a0 += w0s[t2] * tv;
      a1 += w1s[t2] * tv;
    }
    __syncthreads();  // before next chunk overwrites w0s/rA
  }
  out[(size_t)m * TFDIM + c] = 0.5f * (a0 / L0 + a1 / L1);
}

// ---------------------------------------------------------------------------
// K4-fallback (ws too small) — proven streaming attention, unchanged.
// Uses only f32 stage regions + raw bias (no ws).
// ---------------------------------------------------------------------------
__global__ __launch_bounds__(64) void attn_stream(
    const float* __restrict__ bias, const float* __restrict__ stage,
    float* __restrict__ out)
{
  const int lane = threadIdx.x;
  const int m = blockIdx.x;
  const int c0 = lane * 4;

  __shared__ float g0[HIDD], g1[HIDD];
  __shared__ int   ring[256];
  __shared__ float wb0[64], wb1[64];

  const float* gs = stage + (size_t)m * LDO + 512;
  g0[lane]      = gs[lane];
  g0[lane + 64] = gs[lane + 64];
  g1[lane]      = gs[HIDD + lane];
  g1[lane + 64] = gs[HIDD + lane + 64];
  __syncthreads();

  float O0[4] = {0.f, 0.f, 0.f, 0.f};
  float O1[4] = {0.f, 0.f, 0.f, 0.f};
  float M0 = -3.4e38f, M1 = -3.4e38f;
  float L0 = 0.f, L1 = 0.f;

  auto flush = [&](int b, int rp) {
    __syncthreads();
    int j = -1;
    if (lane < b) j = ring[(rp + lane) & 255];
    float s0 = 0.f, s1 = 0.f;
    if (j >= 0) {
      const float* h0 = stage + (size_t)j * LDO + 256;
      const float* h1 = h0 + HIDD;
      #pragma unroll
      for (int d = 0; d < HIDD; d += 4) {
        const f32x4 a = *(const f32x4*)(h0 + d);
        const f32x4 c = *(const f32x4*)(h1 + d);
        #pragma unroll
        for (int e = 0; e < 4; ++e) {
          s0 += g0[d + e] * a[e];
          s1 += g1[d + e] * c[e];
        }
      }
      s0 = (s0 > 0.f) ? s0 : expm1f(s0);
      s1 = (s1 > 0.f) ? s1 : expm1f(s1);
    }
    float m0 = (j >= 0) ? s0 : -3.4e38f;
    float m1 = (j >= 0) ? s1 : -3.4e38f;
    #pragma unroll
    for (int off = 32; off; off >>= 1) {
      m0 = fmaxf(m0, __shfl_xor(m0, off));
      m1 = fmaxf(m1, __shfl_xor(m1, off));
    }
    const float nM0 = fmaxf(M0, m0), nM1 = fmaxf(M1, m1);
    const float w0 = (j >= 0) ? __expf(s0 - nM0) : 0.f;
    const float w1 = (j >= 0) ? __expf(s1 - nM1) : 0.f;
    float l0 = w0, l1 = w1;
    #pragma unroll
    for (int off = 32; off; off >>= 1) {
      l0 += __shfl_xor(l0, off);
      l1 += __shfl_xor(l1, off);
    }
    const float r0 = __expf(M0 - nM0);
    const float r1 = __expf(M1 - nM1);
    L0 = L0 * r0 + l0;  L1 = L1 * r1 + l1;
    M0 = nM0;  M1 = nM1;
    #pragma unroll
    for (int i = 0; i < 4; ++i) { O0[i] *= r0; O1[i] *= r1; }
    wb0[lane] = w0;  wb1[lane] = w1;
    __syncthreads();
    for (int n = 0; n < b; ++n) {
      const int jj = ring[(rp + n) & 255];
      const float wa = wb0[n], wc = wb1[n];
      const f32x4 tv = *(const f32x4*)(stage + (size_t)jj * LDO + c0);
      #pragma unroll
      for (int i = 0; i < 4; ++i) {
        O0[i] += wa * tv[i];
        O1[i] += wc * tv[i];
      }
    }
    __syncthreads();
  };

  const float* brow = bias + (size_t)m * N_SRC;
  int wpos = 0, rpos = 0;
  for (int base = 0; base < N_SRC; base += 256) {
    const f32x4 v = *(const f32x4*)(brow + base + lane * 4);
    #pragma unroll
    for (int e = 0; e < 4; ++e) {
      const bool nz = v[e] > 0.f;
      const unsigned long long mask = __ballot(nz);
      if (nz) {
        const int pos = wpos + __popcll(mask & ((1ull << lane) - 1ull));
        ring[pos & 255] = base + lane * 4 + e;
      }
      wpos += __popcll(mask);
      if (wpos - rpos >= 64) { flush(64, rpos); rpos += 64; }
    }
  }
  while (wpos - rpos > 0) {
    const int b = (wpos - rpos < 64) ? (wpos - rpos) : 64;
    flush(b, rpos);
    rpos += b;
  }

  float* orow = out + (size_t)m * TFDIM + c0;
  if (wpos == 0) {
    float o[4] = {0.f, 0.f, 0.f, 0.f};
    for (int j = 0; j < N_SRC; ++j) {
      const f32x4 tv = *(const f32x4*)(stage + (size_t)j * LDO + c0);
      #pragma unroll
      for (int i = 0; i < 4; ++i) o[i] += tv[i];
    }
    const float inv = 1.f / (float)N_SRC;
    #pragma unroll
    for (int i = 0; i < 4; ++i) orow[i] = o[i] * inv;
  } else {
    const float i0 = 1.f / L0, i1 = 1.f / L1;
    #pragma unroll
    for (int i = 0; i < 4; ++i)
      orow[i] = 0.5f * (O0[i] * i0 + O1[i] * i1);
  }
}

// ---------------------------------------------------------------------------
// K3 — decoder GEMM v2 (ws path): feature_hat = transformed @ dec_W^T + dec_b.
// A from ws bf16 pack (race-free vs in-place OUT writes); B from bf16 dpack.
// 64x64 tiles, grid (128,16) = 2048 blocks, 4 waves. All loads direct bf16x8.
// ---------------------------------------------------------------------------
__global__ __launch_bounds__(256) void gemm_mfma_dec2(
    const unsigned short* __restrict__ apack,  // [8192][256] bf16 bits
    const unsigned short* __restrict__ dpack,  // dec_W [1024][256] bf16 bits
    const float* __restrict__ bias,            // dec_b [1024]
    float* __restrict__ OUT)                   // out1 [8192][1024] f32
{
  const int wave = threadIdx.x >> 6, lane = threadIdx.x & 63;
  const int l15 = lane & 15, quad = lane >> 4;
  const int row0 = blockIdx.x * 64 + wave * 16;
  const int col0 = blockIdx.y * 64;

  const unsigned short* Ap = apack + (size_t)(row0 + l15) * TFDIM + quad * 8;
  const unsigned short* Bp = dpack + (size_t)(col0 + l15) * TFDIM + quad * 8;

  f32x4 acc[4];
  #pragma unroll
  for (int i = 0; i < 4; ++i) acc[i] = (f32x4){0.f, 0.f, 0.f, 0.f};

  #pragma unroll
  for (int k = 0; k < TFDIM; k += 32) {
    const bf16x8 a  = *(const bf16x8*)(Ap + k);
    const bf16x8 b0 = *(const bf16x8*)(Bp + k);
    const bf16x8 b1 = *(const bf16x8*)(Bp + (size_t)16 * TFDIM + k);
    const bf16x8 b2 = *(const bf16x8*)(Bp + (size_t)32 * TFDIM + k);
    const bf16x8 b3 = *(const bf16x8*)(Bp + (size_t)48 * TFDIM + k);
    acc[0] = __builtin_amdgcn_mfma_f32_16x16x32_bf16(a, b0, acc[0], 0, 0, 0);
    acc[1] = __builtin_amdgcn_mfma_f32_16x16x32_bf16(a, b1, acc[1], 0, 0, 0);
    acc[2] = __builtin_amdgcn_mfma_f32_16x16x32_bf16(a, b2, acc[2], 0, 0, 0);
    acc[3] = __builtin_amdgcn_mfma_f32_16x16x32_bf16(a, b3, acc[3], 0, 0, 0);
  }

  #pragma unroll
  for (int ct = 0; ct < 4; ++ct) {
    const int n = col0 + ct * 16 + l15;
    const float bn = bias[n];
    #pragma unroll
    for (int r = 0; r < 4; ++r) {
      const int mm = row0 + quad * 4 + r;
      OUT[(size_t)mm * LDO + n] = acc[ct][r] + bn;
    }
  }
}

// ---------------------------------------------------------------------------
// K3-fallback (ws too small) — in-place decoder GEMM, runs LAST. Block = 32
// rows x all 1024 cols, 128 threads. A staged to LDS (bf16, +8 pad).
// ---------------------------------------------------------------------------
__global__ __launch_bounds__(128) void gemm_mfma_dec(
    const float* __restrict__ W,     // dec_W [1024][256]
    const float* __restrict__ bias,  // dec_b [1024]
    float* __restrict__ OUT)         // out1 [8192][1024] f32
{
  const int row0 = blockIdx.x * 32;
  const int tid = threadIdx.x;
  const int wave = tid >> 6, lane = tid & 63;
  const int l15 = lane & 15, quad = lane >> 4;

  __shared__ __bf16 Ab[32][TFDIM + 8];   // +8 bf16 pad (16 B)

  for (int i = tid; i < 32 * TFDIM; i += 128) {
    const int r = i >> 8, k = i & 255;
    Ab[r][k] = (__bf16)OUT[(size_t)(row0 + r) * LDO + k];
  }
  __syncthreads();

  bf16x8 af[8];
  #pragma unroll
  for (int ks = 0; ks < 8; ++ks)
    af[ks] = *(const bf16x8*)&Ab[wave * 16 + l15][ks * 32 + quad * 8];

  for (int ct = 0; ct < 16; ++ct) {
    f32x4 acc[4];
    #pragma unroll
    for (int i = 0; i < 4; ++i) acc[i] = (f32x4){0.f, 0.f, 0.f, 0.f};
    #pragma unroll
    for (int ks = 0; ks < 8; ++ks) {
      #pragma unroll
      for (int cg = 0; cg < 4; ++cg) {
        const int n = ct * 64 + cg * 16 + l15;
        const bf16x8 bf = load8cvt(W + (size_t)n * TFDIM + ks * 32 + quad * 8);
        acc[cg] = __builtin_amdgcn_mfma_f32_16x16x32_bf16(af[ks], bf, acc[cg], 0, 0, 0);
      }
    }
    #pragma unroll
    for (int cg = 0; cg < 4; ++cg) {
      const int n = ct * 64 + cg * 16 + l15;
      const float bn = bias[n];
      #pragma unroll
      for (int r = 0; r < 4; ++r) {
        const int mm = row0 + wave * 16 + quad * 4 + r;
        OUT[(size_t)mm * LDO + n] = acc[cg][r] + bn;
      }
    }
  }
}

// ---------------------------------------------------------------------------
extern "C" void kernel_launch(void* const* d_in, const int* in_sizes, int n_in,
                              void* d_out, int out_size, void* d_ws, size_t ws_size,
                              hipStream_t stream) {
  const float* bias        = (const float*)d_in[0];
  const float* emb_dest    = (const float*)d_in[1];
  const float* emb_src     = (const float*)d_in[2];
  const float* feature_src = (const float*)d_in[3];
  const float* fc_W        = (const float*)d_in[4];
  const float* fc_b        = (const float*)d_in[5];
  const float* dec_W       = (const float*)d_in[6];
  const float* dec_b       = (const float*)d_in[7];
  const float* att_W       = (const float*)d_in[8];
  const float* att_W2      = (const float*)d_in[9];

  float* out0 = (float*)d_out;                  // feature_src_re [8192][256]
  float* out1 = out0 + (size_t)N_DEST * TFDIM;  // feature_hat   [8192][1024]

  // ws layout: apack 4 MiB | wpack 512 KiB | dpack 512 KiB | hpack 4 MiB
  const size_t apack_bytes = (size_t)N_SRC * TFDIM * sizeof(unsigned short);
  const size_t wpack_bytes = (size_t)TFDIM * FEATD * sizeof(unsigned short);
  const size_t dpack_bytes = (size_t)FEATD * TFDIM * sizeof(unsigned short);
  const size_t hpack_bytes = (size_t)N_SRC * TFDIM * sizeof(unsigned short);
  const bool use_ws =
      (ws_size >= apack_bytes + wpack_bytes + dpack_bytes + hpack_bytes);
  unsigned short* apack = (unsigned short*)d_ws;
  unsigned short* wpack = (unsigned short*)((char*)d_ws + apack_bytes);
  unsigned short* dpack = (unsigned short*)((char*)wpack + wpack_bytes);
  unsigned short* hpack = (unsigned short*)((char*)dpack + dpack_bytes);

  // K0: one-shot weight bf16 conversion
  if (use_ws)
    cvt_weights<<<512, 256, 0, stream>>>(fc_W, dec_W, wpack, dpack);

  // K1: transformed (f32 stage + dense apack) -> out1 staging
  {
    dim3 grid(N_SRC / 64, TFDIM / 64);
    gemm_mfma_k1<<<grid, 256, 0, stream>>>(
        feature_src, fc_W, fc_b, out1,
        use_ws ? apack : (unsigned short*)nullptr,
        use_ws ? wpack : (const unsigned short*)nullptr);
  }
  // K2: h_src (f32 + dense hpack), g_dst (f32)
  proj_all<<<2048, 128, 0, stream>>>(emb_src, emb_dest, att_W, att_W2, out1,
                                     use_ws ? hpack : (unsigned short*)nullptr);
  // K4: fused extraction + attention -> out0 (dense packs, NT bias stream)
  if (use_ws) {
    attn_fused<<<N_DEST, 256, 0, stream>>>(bias, out1, hpack, apack, out0);
  } else {
    attn_stream<<<N_DEST, 64, 0, stream>>>(bias, out1, out0);
  }
  // K3: decoder GEMM, overwrites out1 with feature_hat (LAST)
  if (use_ws) {
    dim3 grid(N_SRC / 64, FEATD / 64);
    gemm_mfma_dec2<<<grid, 256, 0, stream>>>(apack, dpack, dec_b, out1);
  } else {
    gemm_mfma_dec<<<N_SRC / 32, 128, 0, stream>>>(dec_W, dec_b, out1);
  }
}